// Round 1
// baseline (439.584 us; speedup 1.0000x reference)
//
#include <hip/hip_runtime.h>
#include <hip/hip_bf16.h>
#include <stdint.h>

#define N_TOK 32768
#define DIM   1024
#define NC    256
#define GAMMA_F 1e-4f

typedef unsigned short u16;
typedef __attribute__((ext_vector_type(8))) short bf16x8;
typedef __attribute__((ext_vector_type(4))) float f32x4;

// float -> bf16 (round-to-nearest-even); inputs are finite
__device__ __forceinline__ u16 f2b(float f) {
  union { float f; uint32_t u; } c; c.f = f;
  uint32_t u = c.u;
  return (u16)((u + 0x7FFFu + ((u >> 16) & 1u)) >> 16);
}

// async global->LDS, 16B per lane; lds must be the wave-uniform chunk base
__device__ __forceinline__ void gll16(const void* g, void* l) {
  __builtin_amdgcn_global_load_lds(
      (const __attribute__((address_space(1))) unsigned int*)g,
      (__attribute__((address_space(3))) unsigned int*)l, 16, 0, 0);
}

// ---------------------------------------------------------------- K0: X^T -> bf16
__global__ __launch_bounds__(256) void k0_transpose(const float* __restrict__ X,
                                                    u16* __restrict__ TX) {
  __shared__ u16 tile[64][68];                 // +4 pad breaks bank aliasing
  const int n0 = blockIdx.x * 64;
  const int d0 = blockIdx.y * 64;
  const int t = threadIdx.x;
  const int r = t >> 4;                        // 0..15
  const int c4 = (t & 15) * 4;                 // 0..60
#pragma unroll
  for (int i = 0; i < 4; ++i) {
    const int row = r + i * 16;
    const float4 v = *reinterpret_cast<const float4*>(&X[(size_t)(n0 + row) * DIM + d0 + c4]);
    tile[row][c4 + 0] = f2b(v.x);
    tile[row][c4 + 1] = f2b(v.y);
    tile[row][c4 + 2] = f2b(v.z);
    tile[row][c4 + 3] = f2b(v.w);
  }
  __syncthreads();
#pragma unroll
  for (int i = 0; i < 4; ++i) {
    const int drow = r + i * 16;
    ushort4 o;
    o.x = tile[c4 + 0][drow];
    o.y = tile[c4 + 1][drow];
    o.z = tile[c4 + 2][drow];
    o.w = tile[c4 + 3][drow];
    *reinterpret_cast<ushort4*>(&TX[(size_t)(d0 + drow) * N_TOK + n0 + c4]) = o;
  }
}

// ---------------------------------------------------------------- K0w: W -> bf16
__global__ __launch_bounds__(256) void k0_convert_w(const float* __restrict__ W,
                                                    u16* __restrict__ Wb) {
  const int idx = (blockIdx.x * 256 + threadIdx.x) * 4;
  const float4 v = *reinterpret_cast<const float4*>(&W[idx]);
  ushort4 o;
  o.x = f2b(v.x); o.y = f2b(v.y); o.z = f2b(v.z); o.w = f2b(v.w);
  *reinterpret_cast<ushort4*>(&Wb[idx]) = o;
}

// ---------------------------------------------------------------- P1: S = X * Wb^T
// 128x128 tile, K=1024, 4 waves (2x2), A reg-staged f32->bf16, B via global_load_lds
__global__ __launch_bounds__(256, 3) void p1_gemm(const float* __restrict__ X,
                                                  const u16* __restrict__ Wb,
                                                  float* __restrict__ S) {
  __shared__ u16 As[128 * 64];
  __shared__ u16 Bs[128 * 64];
  const int t = threadIdx.x;
  const int lane = t & 63, wave = t >> 6;
  const int wm = wave & 1, wn = wave >> 1;
  const int n0 = blockIdx.x * 128;
  const int c0 = blockIdx.y * 128;
  const int frow = lane & 15, fk = (lane >> 4) * 8;
  const int sr = t >> 3, sc = (t & 7) * 8;
  const int laneoff = lane * 8;
  f32x4 acc[4][4] = {};
  for (int kt = 0; kt < 16; ++kt) {
    const int k0 = kt * 64;
    // A tile [128][64]: load f32, convert, b128 LDS writes (contiguous 1KB/wave)
#pragma unroll
    for (int p = 0; p < 4; ++p) {
      const int row = sr + p * 32;
      const float4 v0 = *reinterpret_cast<const float4*>(&X[(size_t)(n0 + row) * DIM + k0 + sc]);
      const float4 v1 = *reinterpret_cast<const float4*>(&X[(size_t)(n0 + row) * DIM + k0 + sc + 4]);
      bf16x8 u;
      u[0] = (short)f2b(v0.x); u[1] = (short)f2b(v0.y);
      u[2] = (short)f2b(v0.z); u[3] = (short)f2b(v0.w);
      u[4] = (short)f2b(v1.x); u[5] = (short)f2b(v1.y);
      u[6] = (short)f2b(v1.z); u[7] = (short)f2b(v1.w);
      *reinterpret_cast<bf16x8*>(&As[row * 64 + sc]) = u;
    }
    // B tile [128][64] from Wb (bf16 global): async direct-to-LDS
#pragma unroll
    for (int i = 0; i < 4; ++i) {
      const int e = (wave * 4 + i) * 512;      // chunk element base (wave-uniform)
      const int brow = (e + laneoff) >> 6;
      const int bcol = (e + laneoff) & 63;
      gll16(&Wb[(size_t)(c0 + brow) * DIM + k0 + bcol], &Bs[e]);
    }
    __syncthreads();
#pragma unroll
    for (int ks = 0; ks < 2; ++ks) {
      bf16x8 af[4], bg[4];
#pragma unroll
      for (int m = 0; m < 4; ++m)
        af[m] = *reinterpret_cast<const bf16x8*>(&As[(wm * 64 + m * 16 + frow) * 64 + ks * 32 + fk]);
#pragma unroll
      for (int n = 0; n < 4; ++n)
        bg[n] = *reinterpret_cast<const bf16x8*>(&Bs[(wn * 64 + n * 16 + frow) * 64 + ks * 32 + fk]);
#pragma unroll
      for (int m = 0; m < 4; ++m)
#pragma unroll
        for (int n = 0; n < 4; ++n)
          acc[m][n] = __builtin_amdgcn_mfma_f32_16x16x32_bf16(af[m], bg[n], acc[m][n], 0, 0, 0);
    }
    __syncthreads();
  }
#pragma unroll
  for (int m = 0; m < 4; ++m) {
    const int row = wm * 64 + m * 16 + (lane >> 4) * 4;
#pragma unroll
    for (int n = 0; n < 4; ++n) {
      const int col = wn * 64 + n * 16 + frow;
#pragma unroll
      for (int j = 0; j < 4; ++j)
        S[(size_t)(n0 + row + j) * NC + c0 + col] = acc[m][n][j];
    }
  }
}

// ---------------------------------------------------------------- K1s: softmax -> P, P^T
// block = 64 rows; each wave owns one row per iteration (full-wave reduce)
__global__ __launch_bounds__(256) void k1_softmax(const float* __restrict__ S,
                                                  const float* __restrict__ bias,
                                                  u16* __restrict__ P,
                                                  u16* __restrict__ PT) {
  __shared__ u16 T[64][256];
  const int t = threadIdx.x;
  const int w = t >> 6, lane = t & 63;
  const int n0 = blockIdx.x * 64;
  const int col = lane * 4;
  const float4 bv = *reinterpret_cast<const float4*>(&bias[col]);
#pragma unroll
  for (int i = 0; i < 16; ++i) {
    const int row = i * 4 + w;
    float4 v = *reinterpret_cast<const float4*>(&S[(size_t)(n0 + row) * NC + col]);
    v.x += bv.x; v.y += bv.y; v.z += bv.z; v.w += bv.w;
    float mx = fmaxf(fmaxf(v.x, v.y), fmaxf(v.z, v.w));
    for (int s = 1; s < 64; s <<= 1) mx = fmaxf(mx, __shfl_xor(mx, s, 64));
    const float k = 1.44269504088896f;
    const float e0 = exp2f((v.x - mx) * k), e1 = exp2f((v.y - mx) * k);
    const float e2 = exp2f((v.z - mx) * k), e3 = exp2f((v.w - mx) * k);
    float sm = e0 + e1 + e2 + e3;
    for (int s = 1; s < 64; s <<= 1) sm += __shfl_xor(sm, s, 64);
    const float inv = 1.0f / sm;
    ushort4 o;
    o.x = f2b(e0 * inv); o.y = f2b(e1 * inv); o.z = f2b(e2 * inv); o.w = f2b(e3 * inv);
    *reinterpret_cast<ushort4*>(&P[(size_t)(n0 + row) * NC + col]) = o;
    *reinterpret_cast<ushort4*>(&T[row][col]) = o;
  }
  __syncthreads();
  const int c = t;                              // 0..255: one P^T row per thread
#pragma unroll
  for (int g = 0; g < 16; ++g) {
    ushort4 o;
    o.x = T[g * 4 + 0][c];
    o.y = T[g * 4 + 1][c];
    o.z = T[g * 4 + 2][c];
    o.w = T[g * 4 + 3][c];
    *reinterpret_cast<ushort4*>(&PT[(size_t)c * N_TOK + n0 + g * 4]) = o;
  }
}

// ---------------------------------------------------------------- P2: PtX^T partials = TX * PT^T (split-K)
__global__ __launch_bounds__(256, 3) void p2_gemm(const u16* __restrict__ TX,
                                                  const u16* __restrict__ PT,
                                                  float* __restrict__ part) {
  __shared__ u16 As[128 * 64];
  __shared__ u16 Bs[128 * 64];
  const int t = threadIdx.x;
  const int lane = t & 63, wave = t >> 6;
  const int wm = wave & 1, wn = wave >> 1;
  const int sk = blockIdx.x;                    // 0..31
  const int d0 = (blockIdx.y >> 1) * 128;
  const int c0 = (blockIdx.y & 1) * 128;
  const int frow = lane & 15, fk = (lane >> 4) * 8;
  const int laneoff = lane * 8;
  f32x4 acc[4][4] = {};
  for (int kt = 0; kt < 16; ++kt) {
    const size_t k0 = (size_t)sk * 1024 + kt * 64;
#pragma unroll
    for (int i = 0; i < 4; ++i) {
      const int e = (wave * 4 + i) * 512;
      const int brow = (e + laneoff) >> 6;
      const int bcol = (e + laneoff) & 63;
      gll16(&TX[(size_t)(d0 + brow) * N_TOK + k0 + bcol], &As[e]);
      gll16(&PT[(size_t)(c0 + brow) * N_TOK + k0 + bcol], &Bs[e]);
    }
    __syncthreads();
#pragma unroll
    for (int ks = 0; ks < 2; ++ks) {
      bf16x8 af[4], bg[4];
#pragma unroll
      for (int m = 0; m < 4; ++m)
        af[m] = *reinterpret_cast<const bf16x8*>(&As[(wm * 64 + m * 16 + frow) * 64 + ks * 32 + fk]);
#pragma unroll
      for (int n = 0; n < 4; ++n)
        bg[n] = *reinterpret_cast<const bf16x8*>(&Bs[(wn * 64 + n * 16 + frow) * 64 + ks * 32 + fk]);
#pragma unroll
      for (int m = 0; m < 4; ++m)
#pragma unroll
        for (int n = 0; n < 4; ++n)
          acc[m][n] = __builtin_amdgcn_mfma_f32_16x16x32_bf16(af[m], bg[n], acc[m][n], 0, 0, 0);
    }
    __syncthreads();
  }
  float* pl = part + (size_t)sk * (DIM * NC);
#pragma unroll
  for (int m = 0; m < 4; ++m) {
    const int row = wm * 64 + m * 16 + (lane >> 4) * 4;
#pragma unroll
    for (int n = 0; n < 4; ++n) {
      const int colc = wn * 64 + n * 16 + frow;
#pragma unroll
      for (int j = 0; j < 4; ++j)
        pl[(size_t)(d0 + row + j) * NC + c0 + colc] = acc[m][n][j];
    }
  }
}

// ---------------------------------------------------------------- K2r: reduce split-K, fold gamma, -> bf16
__global__ __launch_bounds__(256) void k2_reduce(const float* __restrict__ part,
                                                 u16* __restrict__ PtXb) {
  const int g = (blockIdx.x * 256 + threadIdx.x) * 4;
  f32x4 s = {0.f, 0.f, 0.f, 0.f};
#pragma unroll
  for (int p = 0; p < 32; ++p)
    s += *reinterpret_cast<const f32x4*>(&part[(size_t)p * (DIM * NC) + g]);
  ushort4 o;
  o.x = f2b(s[0] * GAMMA_F); o.y = f2b(s[1] * GAMMA_F);
  o.z = f2b(s[2] * GAMMA_F); o.w = f2b(s[3] * GAMMA_F);
  *reinterpret_cast<ushort4*>(&PtXb[g]) = o;
}

// ---------------------------------------------------------------- P3: Out = X + P * PtXb^T
__global__ __launch_bounds__(256, 3) void p3_gemm(const u16* __restrict__ P,
                                                  const u16* __restrict__ PtXb,
                                                  const float* __restrict__ X,
                                                  float* __restrict__ Out) {
  __shared__ u16 As[128 * 64];
  __shared__ u16 Bs[128 * 64];
  const int t = threadIdx.x;
  const int lane = t & 63, wave = t >> 6;
  const int wm = wave & 1, wn = wave >> 1;
  const int n0 = blockIdx.x * 128;
  const int d0 = blockIdx.y * 128;
  const int frow = lane & 15, fk = (lane >> 4) * 8;
  const int laneoff = lane * 8;
  f32x4 acc[4][4] = {};
  for (int kt = 0; kt < 4; ++kt) {
    const int k0 = kt * 64;
#pragma unroll
    for (int i = 0; i < 4; ++i) {
      const int e = (wave * 4 + i) * 512;
      const int brow = (e + laneoff) >> 6;
      const int bcol = (e + laneoff) & 63;
      gll16(&P[(size_t)(n0 + brow) * NC + k0 + bcol], &As[e]);
      gll16(&PtXb[(size_t)(d0 + brow) * NC + k0 + bcol], &Bs[e]);
    }
    __syncthreads();
#pragma unroll
    for (int ks = 0; ks < 2; ++ks) {
      bf16x8 af[4], bg[4];
#pragma unroll
      for (int m = 0; m < 4; ++m)
        af[m] = *reinterpret_cast<const bf16x8*>(&As[(wm * 64 + m * 16 + frow) * 64 + ks * 32 + fk]);
#pragma unroll
      for (int n = 0; n < 4; ++n)
        bg[n] = *reinterpret_cast<const bf16x8*>(&Bs[(wn * 64 + n * 16 + frow) * 64 + ks * 32 + fk]);
#pragma unroll
      for (int m = 0; m < 4; ++m)
#pragma unroll
        for (int n = 0; n < 4; ++n)
          acc[m][n] = __builtin_amdgcn_mfma_f32_16x16x32_bf16(af[m], bg[n], acc[m][n], 0, 0, 0);
    }
    __syncthreads();
  }
#pragma unroll
  for (int m = 0; m < 4; ++m) {
    const int row = wm * 64 + m * 16 + (lane >> 4) * 4;
#pragma unroll
    for (int n = 0; n < 4; ++n) {
      const int colc = wn * 64 + n * 16 + frow;
#pragma unroll
      for (int j = 0; j < 4; ++j) {
        const size_t off = (size_t)(n0 + row + j) * DIM + d0 + colc;
        Out[off] = X[off] + acc[m][n][j];
      }
    }
  }
}

// ---------------------------------------------------------------- launch
extern "C" void kernel_launch(void* const* d_in, const int* in_sizes, int n_in,
                              void* d_out, int out_size, void* d_ws, size_t ws_size,
                              hipStream_t stream) {
  const float* X = (const float*)d_in[0];
  const float* W = (const float*)d_in[1];
  const float* b = (const float*)d_in[2];
  float* Out = (float*)d_out;
  char* ws = (char*)d_ws;

  // ws layout (bytes): TX 64MB | Wb 0.5MB | PtXb 0.5MB | S/partials 32MB | P 16MB | PT 16MB
  const size_t OFF_TX   = 0;
  const size_t OFF_WB   = (size_t)64 << 20;
  const size_t OFF_PTXB = OFF_WB + ((size_t)512 << 10);
  const size_t OFF_S    = (size_t)65 << 20;          // aliased: S (p1/k1s) then partials (p2/k2r)
  const size_t OFF_P    = (size_t)97 << 20;
  const size_t OFF_PT   = (size_t)113 << 20;
  const size_t NEED     = (size_t)129 << 20;
  if (ws_size < NEED) return;                        // insufficient scratch: leave output poisoned

  u16*   TX   = (u16*)(ws + OFF_TX);
  u16*   Wb   = (u16*)(ws + OFF_WB);
  u16*   PtXb = (u16*)(ws + OFF_PTXB);
  float* S    = (float*)(ws + OFF_S);
  float* part = S;
  u16*   Pp   = (u16*)(ws + OFF_P);
  u16*   PT   = (u16*)(ws + OFF_PT);

  k0_transpose<<<dim3(N_TOK / 64, DIM / 64), 256, 0, stream>>>(X, TX);
  k0_convert_w<<<dim3((NC * DIM) / 1024), 256, 0, stream>>>(W, Wb);
  p1_gemm<<<dim3(N_TOK / 128, NC / 128), 256, 0, stream>>>(X, Wb, S);
  k1_softmax<<<dim3(N_TOK / 64), 256, 0, stream>>>(S, b, Pp, PT);
  p2_gemm<<<dim3(32, 16), 256, 0, stream>>>(TX, PT, part);
  k2_reduce<<<dim3((DIM * NC) / 1024), 256, 0, stream>>>(part, PtXb);
  p3_gemm<<<dim3(N_TOK / 128, DIM / 128), 256, 0, stream>>>(Pp, PtXb, X, Out);
}

// Round 2
// 378.388 us; speedup vs baseline: 1.1617x; 1.1617x over previous
//
#include <hip/hip_runtime.h>
#include <hip/hip_bf16.h>
#include <stdint.h>

#define N_TOK 32768
#define DIM   1024
#define NC    256
#define GAMMA_F 1e-4f

typedef unsigned short u16;
typedef __attribute__((ext_vector_type(8))) short bf16x8;
typedef __attribute__((ext_vector_type(4))) float f32x4;

// float -> bf16 (round-to-nearest-even); inputs are finite
__device__ __forceinline__ u16 f2b(float f) {
  union { float f; uint32_t u; } c; c.f = f;
  uint32_t u = c.u;
  return (u16)((u + 0x7FFFu + ((u >> 16) & 1u)) >> 16);
}

// async global->LDS, 16B per lane; lds arg must be the wave-uniform chunk base
__device__ __forceinline__ void gll16(const void* g, void* l) {
  __builtin_amdgcn_global_load_lds(
      (const __attribute__((address_space(1))) unsigned int*)g,
      (__attribute__((address_space(3))) unsigned int*)l, 16, 0, 0);
}

// Swizzle scheme for [R][64]-bf16 LDS tiles (128B row = 8 x 16B units):
//   slot (row, u) holds global unit u ^ (row&7).
//   staging: lane l of a 512-elem chunk (8 rows) loads global unit (l&7)^(l>>3)
//   reading: global (row, w) is at slot w ^ (row&7)
// Lanes 0..7 then hit 8 distinct 16B units -> all 32 banks once; 2-way overall (free).

// ---------------------------------------------------------------- K0: X^T -> bf16
__global__ __launch_bounds__(256) void k0_transpose(const float* __restrict__ X,
                                                    u16* __restrict__ TX) {
  __shared__ u16 tile[64][68];
  const int n0 = blockIdx.x * 64;
  const int d0 = blockIdx.y * 64;
  const int t = threadIdx.x;
  const int r = t >> 4;
  const int c4 = (t & 15) * 4;
#pragma unroll
  for (int i = 0; i < 4; ++i) {
    const int row = r + i * 16;
    const float4 v = *reinterpret_cast<const float4*>(&X[(size_t)(n0 + row) * DIM + d0 + c4]);
    tile[row][c4 + 0] = f2b(v.x);
    tile[row][c4 + 1] = f2b(v.y);
    tile[row][c4 + 2] = f2b(v.z);
    tile[row][c4 + 3] = f2b(v.w);
  }
  __syncthreads();
#pragma unroll
  for (int i = 0; i < 4; ++i) {
    const int drow = r + i * 16;
    ushort4 o;
    o.x = tile[c4 + 0][drow];
    o.y = tile[c4 + 1][drow];
    o.z = tile[c4 + 2][drow];
    o.w = tile[c4 + 3][drow];
    *reinterpret_cast<ushort4*>(&TX[(size_t)(d0 + drow) * N_TOK + n0 + c4]) = o;
  }
}

// ---------------------------------------------------------------- K0w: W -> bf16
__global__ __launch_bounds__(256) void k0_convert_w(const float* __restrict__ W,
                                                    u16* __restrict__ Wb) {
  const int idx = (blockIdx.x * 256 + threadIdx.x) * 4;
  const float4 v = *reinterpret_cast<const float4*>(&W[idx]);
  ushort4 o;
  o.x = f2b(v.x); o.y = f2b(v.y); o.z = f2b(v.z); o.w = f2b(v.w);
  *reinterpret_cast<ushort4*>(&Wb[idx]) = o;
}

// ---------------------------------------------------------------- P1: S = X*Wb^T -> softmax -> P, P^T
// BM=64 rows, BN=256 (whole C in one pass: X read ONCE). 4 waves (2m x 2n).
// Epilogue: acc -> LDS f32 [64][260], row softmax, write P + swizzled in-place
// bf16, then LDS-transpose -> PT.
__global__ __launch_bounds__(256, 2) void p1_fused(const float* __restrict__ X,
                                                   const u16* __restrict__ Wb,
                                                   const float* __restrict__ bias,
                                                   u16* __restrict__ P,
                                                   u16* __restrict__ PT) {
  __shared__ __align__(16) char smem[66560];      // max(As 8K + Bs 32K, Sf 64*1040)
  u16* As = (u16*)smem;                            // [64][64] bf16, swizzled
  u16* Bs = (u16*)(smem + 8192);                   // [256][64] bf16, swizzled
  const int t = threadIdx.x;
  const int lane = t & 63, wave = t >> 6;
  const int wm = wave & 1, wn = wave >> 1;
  const int n0 = blockIdx.x * 64;
  const int frow = lane & 15, fq = lane >> 4;
  const int au = t & 7, ar0 = t >> 3;              // A staging: unit, row
  const int bug = (lane & 7) ^ (lane >> 3);        // B staging: swizzled global unit

  f32x4 acc[2][8] = {};
  for (int kt = 0; kt < 16; ++kt) {
    const int k0 = kt * 64;
    // A: X f32 [64][64] -> bf16, swizzled ds_write
#pragma unroll
    for (int h = 0; h < 2; ++h) {
      const int r = ar0 + h * 32;
      const size_t gb = (size_t)(n0 + r) * DIM + k0 + au * 8;
      const float4 v0 = *reinterpret_cast<const float4*>(&X[gb]);
      const float4 v1 = *reinterpret_cast<const float4*>(&X[gb + 4]);
      bf16x8 u;
      u[0] = (short)f2b(v0.x); u[1] = (short)f2b(v0.y);
      u[2] = (short)f2b(v0.z); u[3] = (short)f2b(v0.w);
      u[4] = (short)f2b(v1.x); u[5] = (short)f2b(v1.y);
      u[6] = (short)f2b(v1.z); u[7] = (short)f2b(v1.w);
      *reinterpret_cast<bf16x8*>(&As[r * 64 + ((au ^ (r & 7)) * 8)]) = u;
    }
    // B: Wb [256][64] via global_load_lds, pre-swizzled source
#pragma unroll
    for (int i = 0; i < 8; ++i) {
      const int chunk = wave * 8 + i;
      const int brow = chunk * 8 + (lane >> 3);
      gll16(&Wb[(size_t)brow * DIM + k0 + bug * 8], &Bs[chunk * 512]);
    }
    __syncthreads();
#pragma unroll
    for (int ks = 0; ks < 2; ++ks) {
      bf16x8 af[2], bg[8];
#pragma unroll
      for (int m = 0; m < 2; ++m) {
        const int r = wm * 32 + m * 16 + frow;
        af[m] = *reinterpret_cast<const bf16x8*>(&As[r * 64 + (((ks * 4 + fq) ^ (r & 7)) * 8)]);
      }
#pragma unroll
      for (int n = 0; n < 8; ++n) {
        const int r = wn * 128 + n * 16 + frow;
        bg[n] = *reinterpret_cast<const bf16x8*>(&Bs[r * 64 + (((ks * 4 + fq) ^ (r & 7)) * 8)]);
      }
#pragma unroll
      for (int m = 0; m < 2; ++m)
#pragma unroll
        for (int n = 0; n < 8; ++n)
          acc[m][n] = __builtin_amdgcn_mfma_f32_16x16x32_bf16(af[m], bg[n], acc[m][n], 0, 0, 0);
    }
    __syncthreads();
  }
  // ---- epilogue: S tile -> LDS f32 [64][260]
  float* Sf = (float*)smem;
#pragma unroll
  for (int m = 0; m < 2; ++m)
#pragma unroll
    for (int n = 0; n < 8; ++n) {
      const int row = wm * 32 + m * 16 + fq * 4;
      const int col = wn * 128 + n * 16 + frow;
#pragma unroll
      for (int j = 0; j < 4; ++j)
        Sf[(row + j) * 260 + col] = acc[m][n][j];
    }
  __syncthreads();
  // ---- row softmax: wave w owns rows w*16..w*16+15; lane covers cols lane*4..+3
  u16* Su = (u16*)smem;
  const float4 bv = *reinterpret_cast<const float4*>(&bias[lane * 4]);
  const float l2e = 1.44269504088896f;
#pragma unroll
  for (int i = 0; i < 16; ++i) {
    const int row = wave * 16 + i;
    float4 v = *reinterpret_cast<const float4*>(&Sf[row * 260 + lane * 4]);
    v.x += bv.x; v.y += bv.y; v.z += bv.z; v.w += bv.w;
    float mx = fmaxf(fmaxf(v.x, v.y), fmaxf(v.z, v.w));
#pragma unroll
    for (int s = 1; s < 64; s <<= 1) mx = fmaxf(mx, __shfl_xor(mx, s, 64));
    const float e0 = exp2f((v.x - mx) * l2e), e1 = exp2f((v.y - mx) * l2e);
    const float e2 = exp2f((v.z - mx) * l2e), e3 = exp2f((v.w - mx) * l2e);
    float sm = e0 + e1 + e2 + e3;
#pragma unroll
    for (int s = 1; s < 64; s <<= 1) sm += __shfl_xor(sm, s, 64);
    const float inv = 1.0f / sm;
    ushort4 o;
    o.x = f2b(e0 * inv); o.y = f2b(e1 * inv);
    o.z = f2b(e2 * inv); o.w = f2b(e3 * inv);
    *reinterpret_cast<ushort4*>(&P[(size_t)(n0 + row) * NC + lane * 4]) = o;
    // in-place bf16, col-swizzled (c' = c ^ (row&31)) to make the transpose
    // reads conflict-free; all f32 reads of this row completed above (lockstep)
    const int rb = row & 31;
    Su[row * 520 + (((lane * 4 + 0) ^ rb)) * 2] = o.x;
    Su[row * 520 + (((lane * 4 + 1) ^ rb)) * 2] = o.y;
    Su[row * 520 + (((lane * 4 + 2) ^ rb)) * 2] = o.z;
    Su[row * 520 + (((lane * 4 + 3) ^ rb)) * 2] = o.w;
  }
  __syncthreads();
  // ---- PT: quarter-wave per c-row, 16 lanes x ushort4 = 128B contiguous
#pragma unroll
  for (int it = 0; it < 16; ++it) {
    const int c = it * 16 + wave * 4 + fq;
    const int n = frow * 4;
    ushort4 o;
    o.x = Su[(n + 0) * 520 + ((c ^ ((n + 0) & 31))) * 2];
    o.y = Su[(n + 1) * 520 + ((c ^ ((n + 1) & 31))) * 2];
    o.z = Su[(n + 2) * 520 + ((c ^ ((n + 2) & 31))) * 2];
    o.w = Su[(n + 3) * 520 + ((c ^ ((n + 3) & 31))) * 2];
    *reinterpret_cast<ushort4*>(&PT[(size_t)c * N_TOK + n0 + n]) = o;
  }
}

// ---------------------------------------------------------------- P2: PtX^T partials = TX * PT^T (split-K)
__global__ __launch_bounds__(256, 2) void p2_gemm(const u16* __restrict__ TX,
                                                  const u16* __restrict__ PT,
                                                  float* __restrict__ part) {
  __shared__ __align__(16) char smem[67584];       // max(As+Bs 32K, Cf 128*132*4)
  u16* As = (u16*)smem;
  u16* Bs = (u16*)(smem + 16384);
  const int t = threadIdx.x;
  const int lane = t & 63, wave = t >> 6;
  const int wm = wave & 1, wn = wave >> 1;
  const int sk = blockIdx.x;                       // 0..31
  const int d0 = (blockIdx.y >> 1) * 128;
  const int c0 = (blockIdx.y & 1) * 128;
  const int frow = lane & 15, fq = lane >> 4;
  const int srow = lane >> 3;
  const int bug = (lane & 7) ^ (lane >> 3);
  f32x4 acc[4][4] = {};
  for (int kt = 0; kt < 16; ++kt) {
    const size_t k0 = (size_t)sk * 1024 + kt * 64;
#pragma unroll
    for (int i = 0; i < 4; ++i) {
      const int chunk = wave * 4 + i;
      const int r = chunk * 8 + srow;
      gll16(&TX[(size_t)(d0 + r) * N_TOK + k0 + bug * 8], &As[chunk * 512]);
      gll16(&PT[(size_t)(c0 + r) * N_TOK + k0 + bug * 8], &Bs[chunk * 512]);
    }
    __syncthreads();
#pragma unroll
    for (int ks = 0; ks < 2; ++ks) {
      bf16x8 af[4], bg[4];
#pragma unroll
      for (int m = 0; m < 4; ++m) {
        const int r = wm * 64 + m * 16 + frow;
        af[m] = *reinterpret_cast<const bf16x8*>(&As[r * 64 + (((ks * 4 + fq) ^ (r & 7)) * 8)]);
      }
#pragma unroll
      for (int n = 0; n < 4; ++n) {
        const int r = wn * 64 + n * 16 + frow;
        bg[n] = *reinterpret_cast<const bf16x8*>(&Bs[r * 64 + (((ks * 4 + fq) ^ (r & 7)) * 8)]);
      }
#pragma unroll
      for (int m = 0; m < 4; ++m)
#pragma unroll
        for (int n = 0; n < 4; ++n)
          acc[m][n] = __builtin_amdgcn_mfma_f32_16x16x32_bf16(af[m], bg[n], acc[m][n], 0, 0, 0);
    }
    __syncthreads();
  }
  // LDS-staged coalesced store
  float* Cf = (float*)smem;                        // [128][132]
#pragma unroll
  for (int m = 0; m < 4; ++m)
#pragma unroll
    for (int n = 0; n < 4; ++n) {
      const int row = wm * 64 + m * 16 + fq * 4;
      const int col = wn * 64 + n * 16 + frow;
#pragma unroll
      for (int j = 0; j < 4; ++j)
        Cf[(row + j) * 132 + col] = acc[m][n][j];
    }
  __syncthreads();
  float* pl = part + (size_t)sk * (DIM * NC);
  const int cl = (t & 31) * 4;
  const int rr = t >> 5;
#pragma unroll
  for (int p = 0; p < 16; ++p) {
    const int row = p * 8 + rr;
    const float4 v = *reinterpret_cast<const float4*>(&Cf[row * 132 + cl]);
    *reinterpret_cast<float4*>(&pl[(size_t)(d0 + row) * NC + c0 + cl]) = v;
  }
}

// ---------------------------------------------------------------- K2r: reduce split-K, fold gamma, -> bf16
__global__ __launch_bounds__(256) void k2_reduce(const float* __restrict__ part,
                                                 u16* __restrict__ PtXb) {
  const int g = (blockIdx.x * 256 + threadIdx.x) * 4;
  f32x4 s = {0.f, 0.f, 0.f, 0.f};
#pragma unroll
  for (int p = 0; p < 32; ++p)
    s += *reinterpret_cast<const f32x4*>(&part[(size_t)p * (DIM * NC) + g]);
  ushort4 o;
  o.x = f2b(s[0] * GAMMA_F); o.y = f2b(s[1] * GAMMA_F);
  o.z = f2b(s[2] * GAMMA_F); o.w = f2b(s[3] * GAMMA_F);
  *reinterpret_cast<ushort4*>(&PtXb[g]) = o;
}

// ---------------------------------------------------------------- P3: Out = X + P * PtXb^T
__global__ __launch_bounds__(256, 2) void p3_gemm(const u16* __restrict__ P,
                                                  const u16* __restrict__ PtXb,
                                                  const float* __restrict__ X,
                                                  float* __restrict__ Out) {
  __shared__ __align__(16) char smem[67584];
  u16* As = (u16*)smem;
  u16* Bs = (u16*)(smem + 16384);
  const int t = threadIdx.x;
  const int lane = t & 63, wave = t >> 6;
  const int wm = wave & 1, wn = wave >> 1;
  const int n0 = blockIdx.x * 128;
  const int d0 = blockIdx.y * 128;
  const int frow = lane & 15, fq = lane >> 4;
  const int srow = lane >> 3;
  const int bug = (lane & 7) ^ (lane >> 3);
  f32x4 acc[4][4] = {};
  for (int kt = 0; kt < 4; ++kt) {
    const int k0 = kt * 64;
#pragma unroll
    for (int i = 0; i < 4; ++i) {
      const int chunk = wave * 4 + i;
      const int r = chunk * 8 + srow;
      gll16(&P[(size_t)(n0 + r) * NC + k0 + bug * 8], &As[chunk * 512]);
      gll16(&PtXb[(size_t)(d0 + r) * NC + k0 + bug * 8], &Bs[chunk * 512]);
    }
    __syncthreads();
#pragma unroll
    for (int ks = 0; ks < 2; ++ks) {
      bf16x8 af[4], bg[4];
#pragma unroll
      for (int m = 0; m < 4; ++m) {
        const int r = wm * 64 + m * 16 + frow;
        af[m] = *reinterpret_cast<const bf16x8*>(&As[r * 64 + (((ks * 4 + fq) ^ (r & 7)) * 8)]);
      }
#pragma unroll
      for (int n = 0; n < 4; ++n) {
        const int r = wn * 64 + n * 16 + frow;
        bg[n] = *reinterpret_cast<const bf16x8*>(&Bs[r * 64 + (((ks * 4 + fq) ^ (r & 7)) * 8)]);
      }
#pragma unroll
      for (int m = 0; m < 4; ++m)
#pragma unroll
        for (int n = 0; n < 4; ++n)
          acc[m][n] = __builtin_amdgcn_mfma_f32_16x16x32_bf16(af[m], bg[n], acc[m][n], 0, 0, 0);
    }
    __syncthreads();
  }
  // LDS-staged epilogue: coalesced float4 X-read + Out-write
  float* Cf = (float*)smem;                        // [128][132]
#pragma unroll
  for (int m = 0; m < 4; ++m)
#pragma unroll
    for (int n = 0; n < 4; ++n) {
      const int row = wm * 64 + m * 16 + fq * 4;
      const int col = wn * 64 + n * 16 + frow;
#pragma unroll
      for (int j = 0; j < 4; ++j)
        Cf[(row + j) * 132 + col] = acc[m][n][j];
    }
  __syncthreads();
  const int cl = (t & 31) * 4;
  const int rr = t >> 5;
#pragma unroll
  for (int p = 0; p < 16; ++p) {
    const int row = p * 8 + rr;
    float4 v = *reinterpret_cast<const float4*>(&Cf[row * 132 + cl]);
    const size_t off = (size_t)(n0 + row) * DIM + d0 + cl;
    const float4 x = *reinterpret_cast<const float4*>(&X[off]);
    v.x += x.x; v.y += x.y; v.z += x.z; v.w += x.w;
    *reinterpret_cast<float4*>(&Out[off]) = v;
  }
}

// ---------------------------------------------------------------- launch
extern "C" void kernel_launch(void* const* d_in, const int* in_sizes, int n_in,
                              void* d_out, int out_size, void* d_ws, size_t ws_size,
                              hipStream_t stream) {
  const float* X = (const float*)d_in[0];
  const float* W = (const float*)d_in[1];
  const float* b = (const float*)d_in[2];
  float* Out = (float*)d_out;
  char* ws = (char*)d_ws;

  // ws layout (bytes): TX 64MB | Wb 0.5MB | PtXb 0.5MB | partials 32MB | P 16MB | PT 16MB
  const size_t OFF_TX   = 0;
  const size_t OFF_WB   = (size_t)64 << 20;
  const size_t OFF_PTXB = OFF_WB + ((size_t)512 << 10);
  const size_t OFF_PART = (size_t)65 << 20;
  const size_t OFF_P    = (size_t)97 << 20;
  const size_t OFF_PT   = (size_t)113 << 20;
  const size_t NEED     = (size_t)129 << 20;
  if (ws_size < NEED) return;

  u16*   TX   = (u16*)(ws + OFF_TX);
  u16*   Wb   = (u16*)(ws + OFF_WB);
  u16*   PtXb = (u16*)(ws + OFF_PTXB);
  float* part = (float*)(ws + OFF_PART);
  u16*   Pp   = (u16*)(ws + OFF_P);
  u16*   PT   = (u16*)(ws + OFF_PT);

  k0_transpose<<<dim3(N_TOK / 64, DIM / 64), 256, 0, stream>>>(X, TX);
  k0_convert_w<<<dim3((NC * DIM) / 1024), 256, 0, stream>>>(W, Wb);
  p1_fused<<<dim3(N_TOK / 64), 256, 0, stream>>>(X, Wb, b, Pp, PT);
  p2_gemm<<<dim3(32, 16), 256, 0, stream>>>(TX, PT, part);
  k2_reduce<<<dim3((DIM * NC) / 1024), 256, 0, stream>>>(part, PtXb);
  p3_gemm<<<dim3(N_TOK / 128, DIM / 128), 256, 0, stream>>>(Pp, PtXb, X, Out);
}